// Round 1
// baseline (380.641 us; speedup 1.0000x reference)
//
#include <hip/hip_runtime.h>

#define FUSE_K 20
#define NCH 16

// One thread per output element (n, c).
//  - c = gid & 15 : 16 consecutive lanes gather one contiguous 64B src_feat row -> coalesced
//  - map row values broadcast across the 16 lanes (same-address load, L1-served)
__global__ __launch_bounds__(256) void VoxelPooling_kernel(
    const int* __restrict__ invoxel_map,   // (N, FUSE_K) int32
    const float* __restrict__ src_feat,    // (M, NCH) float32
    float* __restrict__ out,               // (N, NCH) float32
    int n_total)                           // N * NCH
{
    int gid = blockIdx.x * blockDim.x + threadIdx.x;
    if (gid >= n_total) return;

    int n = gid >> 4;        // voxel index
    int c = gid & 15;        // channel index

    const int* mrow = invoxel_map + n * FUSE_K;

    int idx0 = mrow[0];
    float acc = 0.0f;
#pragma unroll
    for (int k = 0; k < FUSE_K; ++k) {
        int idx = mrow[k];
        idx = (idx == 0) ? idx0 : idx;
        acc += src_feat[idx * NCH + c];
    }
    out[gid] = acc * (1.0f / FUSE_K);
}

extern "C" void kernel_launch(void* const* d_in, const int* in_sizes, int n_in,
                              void* d_out, int out_size, void* d_ws, size_t ws_size,
                              hipStream_t stream) {
    // d_in[0] = invoxel_xyz (float32, UNUSED by the reference)
    // d_in[1] = invoxel_map (integer -> int32 per harness contract)
    // d_in[2] = src_feat    (float32)
    const int*   invoxel_map = (const int*)d_in[1];
    const float* src_feat    = (const float*)d_in[2];
    float*       out         = (float*)d_out;

    int n_total = out_size;  // N * 16
    int block = 256;
    int grid = (n_total + block - 1) / block;

    VoxelPooling_kernel<<<grid, block, 0, stream>>>(invoxel_map, src_feat, out, n_total);
}